// Round 3
// baseline (271.015 us; speedup 1.0000x reference)
//
#include <hip/hip_runtime.h>

#define EPSV 1e-5f

// ---------------- K1: 4x4 avg-pool + GroupNorm(32) + SiLU ----------------
// grid 512 = B(16) x G(32), block 256 (one thread per pooled pixel)
__global__ __launch_bounds__(256) void k1_pool_gn1(
    const float* __restrict__ x, const float* __restrict__ g1, const float* __restrict__ b1,
    float* __restrict__ a1)
{
    const int blk = blockIdx.x;
    const int b = blk >> 5, g = blk & 31;
    const int t = threadIdx.x;
    const int ph = t >> 4, pw = t & 15;

    float v[10];
    float s = 0.f, ss = 0.f;
#pragma unroll
    for (int k = 0; k < 10; ++k) {
        const int c = g * 10 + k;
        const float* base = x + (((size_t)(b * 320 + c)) * 64 + ph * 4) * 64 + pw * 4;
        float acc = 0.f;
#pragma unroll
        for (int i = 0; i < 4; ++i) {
            const float4 r = *reinterpret_cast<const float4*>(base + i * 64);
            acc += r.x + r.y + r.z + r.w;
        }
        v[k] = acc * (1.f / 16.f);
        s += v[k];
        ss += v[k] * v[k];
    }

    __shared__ float rs[4], rss[4];
#pragma unroll
    for (int off = 32; off; off >>= 1) {
        s += __shfl_down(s, off);
        ss += __shfl_down(ss, off);
    }
    const int wid = t >> 6, lane = t & 63;
    if (lane == 0) { rs[wid] = s; rss[wid] = ss; }
    __syncthreads();
    const float S = rs[0] + rs[1] + rs[2] + rs[3];
    const float SS = rss[0] + rss[1] + rss[2] + rss[3];
    const float mean = S * (1.f / 2560.f);
    const float var = SS * (1.f / 2560.f) - mean * mean;
    const float inv = rsqrtf(var + EPSV);

#pragma unroll
    for (int k = 0; k < 10; ++k) {
        const int c = g * 10 + k;
        const float xn = (v[k] - mean) * inv * g1[c] + b1[c];
        const float y = xn / (1.f + __expf(-xn));
        a1[((size_t)(b * 320 + c)) * 256 + t] = y;
    }
}

// ---------------- K2: conv3x3 320->8 on 16x16, chunked over channels ----------------
// grid 256 = B(16) x chunks(16 of 20 channels), block 256 (one thread per pixel)
// NO atomics: each chunk writes its partial sums to a private slab z0p[b][ch][8][256].
__global__ __launch_bounds__(256) void k2_conv1(
    const float* __restrict__ a1, const float* __restrict__ w1, float* __restrict__ z0p)
{
    const int b = blockIdx.x >> 4, ch = blockIdx.x & 15;
    const int t = threadIdx.x;
    const int ph = t >> 4, pw = t & 15;
    const int c0 = ch * 20;

    __shared__ __align__(16) float tiles[20 * 256];
    __shared__ float lw[8 * 20 * 9];

    {
        const float4* src = reinterpret_cast<const float4*>(a1 + (size_t)(b * 320 + c0) * 256);
        float4* dst = reinterpret_cast<float4*>(tiles);
        for (int i = t; i < 1280; i += 256) dst[i] = src[i];
    }
    for (int i = t; i < 1440; i += 256) {
        const int o = i / 180, rem = i % 180, cc = rem / 9, k = rem % 9;
        lw[i] = w1[(o * 320 + c0 + cc) * 9 + k];
    }
    __syncthreads();

    float acc[8] = {0.f, 0.f, 0.f, 0.f, 0.f, 0.f, 0.f, 0.f};
    for (int cc = 0; cc < 20; ++cc) {
        const float* tp = &tiles[cc * 256];
#pragma unroll
        for (int ky = 0; ky < 3; ++ky) {
            const int yy = ph + ky - 1;
            if ((unsigned)yy > 15u) continue;
#pragma unroll
            for (int kx = 0; kx < 3; ++kx) {
                const int xx = pw + kx - 1;
                if ((unsigned)xx > 15u) continue;
                const float val = tp[yy * 16 + xx];
                const int wi = cc * 9 + ky * 3 + kx;
#pragma unroll
                for (int o = 0; o < 8; ++o) acc[o] += lw[o * 180 + wi] * val;
            }
        }
    }
    float* zp = z0p + (size_t)blockIdx.x * 2048 + t;   // [b][ch][o][t]
#pragma unroll
    for (int o = 0; o < 8; ++o) zp[o * 256] = acc[o];
}

// ---------------- K3 fused (no atomics): reduce partials -> GN(8)+qkv -> attn -> proj/LN/MLP -> GN2+SiLU ----------------
// grid 16 = B, block 1024 (16 waves). All intermediates in LDS.
// Attention: wave wv = (h = wv>>2, mq = wv&3); thread owns 4 pixels; per-wave
// partials go to part[wv][n][{l,o0,o1}] (stride 3, coprime with 32 banks),
// reduced deterministically by threads 0..255 after a barrier.
__global__ __launch_bounds__(1024) void k3_fused(
    const float* __restrict__ z0p, const float* __restrict__ b_conv1,
    const float* __restrict__ ga, const float* __restrict__ ba,
    const float* __restrict__ w_qkv, const float* __restrict__ b_qkv,
    const float* __restrict__ w_proj, const float* __restrict__ b_proj,
    const float* __restrict__ ln_g, const float* __restrict__ ln_b,
    const float* __restrict__ w_fc1, const float* __restrict__ b_fc1,
    const float* __restrict__ w_fc2, const float* __restrict__ b_fc2,
    const float* __restrict__ g2, const float* __restrict__ b2,
    float* __restrict__ a2)
{
    const int b = blockIdx.x, t = threadIdx.x;
    const int wv = t >> 6, lane = t & 63;

    __shared__ float zsh[8][256];            //  8 KB: z0, later z2
    __shared__ float stats[16];
    __shared__ float2 qsh[4][256];           //  8 KB
    __shared__ float4 kvsh[4][256];          // 16 KB
    __shared__ float part[16][256][3];       // 48 KB: per-wave attn partials

    // ---- Phase A: reduce 16 conv1 chunk-partials + bias -> zsh (1024 thr, one float2 each)
    {
        const int c = t >> 7;                // channel of this float2 pair (2t>>8)
        float2 acc = make_float2(b_conv1[c], b_conv1[c]);
        const float2* pp = reinterpret_cast<const float2*>(z0p + (size_t)b * 32768) + t;
        for (int ch = 0; ch < 16; ++ch) {
            const float2 v = pp[ch * 1024];
            acc.x += v.x; acc.y += v.y;
        }
        reinterpret_cast<float2*>(&zsh[0][0])[t] = acc;
    }
    __syncthreads();

    // ---- GN(8) stats: one wave per channel
    if (wv < 8) {
        const int c = wv;
        const float a0 = zsh[c][lane], a1 = zsh[c][lane + 64];
        const float a2v = zsh[c][lane + 128], a3 = zsh[c][lane + 192];
        float s = a0 + a1 + a2v + a3;
        float ss = a0 * a0 + a1 * a1 + a2v * a2v + a3 * a3;
#pragma unroll
        for (int off = 32; off; off >>= 1) {
            s += __shfl_down(s, off);
            ss += __shfl_down(ss, off);
        }
        if (lane == 0) {
            const float m = s * (1.f / 256.f);
            const float vv = ss * (1.f / 256.f) - m * m;
            stats[2 * c] = m;
            stats[2 * c + 1] = rsqrtf(vv + EPSV);
        }
    }
    __syncthreads();

    // ---- qkv projection (threads 0..255, one pixel each)
    if (t < 256) {
        float gn[8];
#pragma unroll
        for (int c = 0; c < 8; ++c)
            gn[c] = (zsh[c][t] - stats[2 * c]) * stats[2 * c + 1] * ga[c] + ba[c];
        float qv[24];
#pragma unroll
        for (int o = 0; o < 24; ++o) {
            float acc = b_qkv[o];
#pragma unroll
            for (int c = 0; c < 8; ++c) acc += w_qkv[o * 8 + c] * gn[c];
            qv[o] = acc;
        }
        // q pre-scaled by dh^-0.5 * log2(e) so attention inner loop is dot+exp2
        const float lscale = 0.70710678118654752f * 1.44269504088896341f;
#pragma unroll
        for (int h = 0; h < 4; ++h) {
            qsh[h][t]  = make_float2(qv[2 * h] * lscale, qv[2 * h + 1] * lscale);
            kvsh[h][t] = make_float4(qv[8 + 2 * h], qv[9 + 2 * h], qv[16 + 2 * h], qv[17 + 2 * h]);
        }
    }
    __syncthreads();

    // ---- attention (max-free softmax; scores bounded |s|<~3)
    {
        const int h = wv >> 2, mq = wv & 3;
        float qx[4], qy[4], l[4], o0[4], o1[4];
#pragma unroll
        for (int k = 0; k < 4; ++k) {
            const float2 q = qsh[h][lane + 64 * k];
            qx[k] = q.x; qy[k] = q.y;
            l[k] = 0.f; o0[k] = 0.f; o1[k] = 0.f;
        }
        const float4* kp = &kvsh[h][mq * 64];
#pragma unroll 8
        for (int i = 0; i < 64; ++i) {
            const float4 kvv = kp[i];
#pragma unroll
            for (int k = 0; k < 4; ++k) {
                const float e = __builtin_exp2f(qx[k] * kvv.x + qy[k] * kvv.y);
                l[k] += e;
                o0[k] += e * kvv.z;
                o1[k] += e * kvv.w;
            }
        }
#pragma unroll
        for (int k = 0; k < 4; ++k) {
            const int n = lane + 64 * k;
            part[wv][n][0] = l[k];
            part[wv][n][1] = o0[k];
            part[wv][n][2] = o1[k];
        }
    }
    __syncthreads();

    // ---- proj+res, LN, MLP+res (threads 0..255, one pixel each)
    float z2r[8];
    if (t < 256) {
        float ao[8];
#pragma unroll
        for (int h = 0; h < 4; ++h) {
            float L = 0.f, O0 = 0.f, O1 = 0.f;
#pragma unroll
            for (int mq = 0; mq < 4; ++mq) {
                const int w = h * 4 + mq;
                L  += part[w][t][0];
                O0 += part[w][t][1];
                O1 += part[w][t][2];
            }
            const float rl = 1.f / L;
            ao[2 * h]     = O0 * rl;
            ao[2 * h + 1] = O1 * rl;
        }
        float z1[8];
#pragma unroll
        for (int o = 0; o < 8; ++o) {
            float acc = b_proj[o];
#pragma unroll
            for (int c = 0; c < 8; ++c) acc += w_proj[o * 8 + c] * ao[c];
            z1[o] = zsh[o][t] + acc;
        }
        float mu = 0.f;
#pragma unroll
        for (int c = 0; c < 8; ++c) mu += z1[c];
        mu *= 0.125f;
        float var = 0.f;
#pragma unroll
        for (int c = 0; c < 8; ++c) { const float d = z1[c] - mu; var += d * d; }
        var *= 0.125f;
        const float linv = rsqrtf(var + EPSV);
        float ln[8];
#pragma unroll
        for (int c = 0; c < 8; ++c) ln[c] = (z1[c] - mu) * linv * ln_g[c] + ln_b[c];
        float hg[16];
#pragma unroll
        for (int o = 0; o < 16; ++o) {
            float hv = b_fc1[o];
#pragma unroll
            for (int c = 0; c < 8; ++c) hv += w_fc1[o * 8 + c] * ln[c];
            hg[o] = 0.5f * hv * (1.f + erff(hv * 0.70710678f));
        }
#pragma unroll
        for (int c = 0; c < 8; ++c) {
            float acc = b_fc2[c];
#pragma unroll
            for (int o = 0; o < 16; ++o) acc += w_fc2[c * 16 + o] * hg[o];
            z2r[c] = z1[c] + acc;
        }
        // stage z2 (each thread touches only its own column -> no cross-thread hazard)
#pragma unroll
        for (int c = 0; c < 8; ++c) zsh[c][t] = z2r[c];
    }
    __syncthreads();

    // ---- GN2 stats on pre-upsample map (repeat preserves mean/var)
    if (wv < 8) {
        const int c = wv;
        const float a0 = zsh[c][lane], a1 = zsh[c][lane + 64];
        const float a2v = zsh[c][lane + 128], a3 = zsh[c][lane + 192];
        float s = a0 + a1 + a2v + a3;
        float ss = a0 * a0 + a1 * a1 + a2v * a2v + a3 * a3;
#pragma unroll
        for (int off = 32; off; off >>= 1) {
            s += __shfl_down(s, off);
            ss += __shfl_down(ss, off);
        }
        if (lane == 0) {
            const float m = s * (1.f / 256.f);
            const float vv = ss * (1.f / 256.f) - m * m;
            stats[2 * c] = m;
            stats[2 * c + 1] = rsqrtf(vv + EPSV);
        }
    }
    __syncthreads();

    if (t < 256) {
#pragma unroll
        for (int c = 0; c < 8; ++c) {
            const float xn = (z2r[c] - stats[2 * c]) * stats[2 * c + 1] * g2[c] + b2[c];
            a2[(size_t)b * 2048 + c * 256 + t] = xn / (1.f + __expf(-xn));
        }
    }
}

// ---------------- K4: upsample-on-the-fly conv3x3 8->320 on 64x64 ----------------
// Upsampled input is piecewise-constant over 4x4 cells: the 16 outputs per
// cell take only 9 distinct values. ~25 FMA + ~24 adds per channel vs 144 FMA.
// grid (320, 16) = (out-channel, batch), block 256 (one thread per 4x4 cell)
__global__ __launch_bounds__(256) void k4_conv2(
    const float* __restrict__ a2, const float* __restrict__ w2,
    const float* __restrict__ bc2, float* __restrict__ out)
{
    const int o = blockIdx.x, b = blockIdx.y, t = threadIdx.x;
    __shared__ float A[8 * 324];   // (8, 18, 18) zero-halo padded pooled map
    __shared__ float wsh[72];

    for (int i = t; i < 2592; i += 256) A[i] = 0.f;
    if (t < 72) wsh[t] = w2[o * 72 + t];
    __syncthreads();
    for (int i = t; i < 2048; i += 256) {
        const int c = i >> 8, y = (i >> 4) & 15, x = i & 15;
        A[c * 324 + (y + 1) * 18 + (x + 1)] = a2[(size_t)b * 2048 + i];
    }
    __syncthreads();

    const int cy = t >> 4, cx = t & 15;
    const float bias = bc2[o];
    float acc[3][3];
#pragma unroll
    for (int r = 0; r < 3; ++r)
#pragma unroll
        for (int s = 0; s < 3; ++s) acc[r][s] = bias;

    const float* Abase = &A[cy * 18 + cx];
#pragma unroll
    for (int c = 0; c < 8; ++c) {
        const float C00 = Abase[c * 324 + 0 * 18 + 0], C01 = Abase[c * 324 + 0 * 18 + 1], C02 = Abase[c * 324 + 0 * 18 + 2];
        const float C10 = Abase[c * 324 + 1 * 18 + 0], C11 = Abase[c * 324 + 1 * 18 + 1], C12 = Abase[c * 324 + 1 * 18 + 2];
        const float C20 = Abase[c * 324 + 2 * 18 + 0], C21 = Abase[c * 324 + 2 * 18 + 1], C22 = Abase[c * 324 + 2 * 18 + 2];

        const float k0 = wsh[c * 9 + 0], k1 = wsh[c * 9 + 1], k2 = wsh[c * 9 + 2];
        const float k3 = wsh[c * 9 + 3], k4 = wsh[c * 9 + 4], k5 = wsh[c * 9 + 5];
        const float k6 = wsh[c * 9 + 6], k7 = wsh[c * 9 + 7], k8 = wsh[c * 9 + 8];

        const float q12x = k3 + k6, q12y = k4 + k7, q12z = k5 + k8;
        const float q01x = k0 + k3, q01y = k1 + k4, q01z = k2 + k5;
        const float qax = q12x + k0, qay = q12y + k1, qaz = q12z + k2;

        const float r0_c12 = k1 + k2,      r0_c012 = r0_c12 + k0,     r0_c01 = k0 + k1;
        const float q12_c12 = q12y + q12z, q12_c012 = q12_c12 + q12x, q12_c01 = q12x + q12y;
        const float qa_c12 = qay + qaz,    qa_c012 = qa_c12 + qax,    qa_c01 = qax + qay;
        const float q01_c12 = q01y + q01z, q01_c012 = q01_c12 + q01x, q01_c01 = q01x + q01y;
        const float r2_c12 = k7 + k8,      r2_c012 = r2_c12 + k6,     r2_c01 = k6 + k7;

        acc[0][0] += k0 * C00 + r0_c12 * C01 + q12x * C10 + q12_c12 * C11;
        acc[0][1] += r0_c012 * C01 + q12_c012 * C11;
        acc[0][2] += r0_c01 * C01 + k2 * C02 + q12_c01 * C11 + q12z * C12;
        acc[1][0] += qax * C10 + qa_c12 * C11;
        acc[1][1] += qa_c012 * C11;
        acc[1][2] += qa_c01 * C11 + qaz * C12;
        acc[2][0] += q01x * C10 + q01_c12 * C11 + k6 * C20 + r2_c12 * C21;
        acc[2][1] += q01_c012 * C11 + r2_c012 * C21;
        acc[2][2] += q01_c01 * C11 + q01z * C12 + r2_c01 * C21 + k8 * C22;
    }

    const size_t base = ((size_t)(b * 320 + o)) * 4096;
    const int rowmap[4] = {0, 1, 1, 2};
#pragma unroll
    for (int py = 0; py < 4; ++py) {
        const int r = rowmap[py];
        const float4 v = make_float4(acc[r][0], acc[r][1], acc[r][1], acc[r][2]);
        *reinterpret_cast<float4*>(out + base + (cy * 4 + py) * 64 + cx * 4) = v;
    }
}

extern "C" void kernel_launch(void* const* d_in, const int* in_sizes, int n_in,
                              void* d_out, int out_size, void* d_ws, size_t ws_size,
                              hipStream_t stream) {
    const float* x       = (const float*)d_in[0];
    const float* g1      = (const float*)d_in[1];
    const float* b1      = (const float*)d_in[2];
    const float* w_conv1 = (const float*)d_in[3];
    const float* b_conv1 = (const float*)d_in[4];
    const float* ga      = (const float*)d_in[5];
    const float* ba      = (const float*)d_in[6];
    const float* w_qkv   = (const float*)d_in[7];
    const float* b_qkv   = (const float*)d_in[8];
    const float* w_proj  = (const float*)d_in[9];
    const float* b_proj  = (const float*)d_in[10];
    const float* ln_g    = (const float*)d_in[11];
    const float* ln_b    = (const float*)d_in[12];
    const float* w_fc1   = (const float*)d_in[13];
    const float* b_fc1   = (const float*)d_in[14];
    const float* w_fc2   = (const float*)d_in[15];
    const float* b_fc2   = (const float*)d_in[16];
    const float* g2      = (const float*)d_in[17];
    const float* b2      = (const float*)d_in[18];
    const float* w_conv2 = (const float*)d_in[19];
    const float* b_conv2 = (const float*)d_in[20];

    float* a1  = (float*)d_ws;            // 1,310,720 floats
    float* z0p = a1 + 1310720;            //   524,288 (16 b x 16 chunks x 2048)
    float* a2  = z0p + 524288;            //    32,768
    float* out = (float*)d_out;

    k1_pool_gn1<<<512, 256, 0, stream>>>(x, g1, b1, a1);
    k2_conv1<<<256, 256, 0, stream>>>(a1, w_conv1, z0p);
    k3_fused<<<16, 1024, 0, stream>>>(z0p, b_conv1, ga, ba, w_qkv, b_qkv,
                                      w_proj, b_proj, ln_g, ln_b,
                                      w_fc1, b_fc1, w_fc2, b_fc2, g2, b2, a2);
    k4_conv2<<<dim3(320, 16), 256, 0, stream>>>(a2, w_conv2, b_conv2, out);
}

// Round 4
// 257.817 us; speedup vs baseline: 1.0512x; 1.0512x over previous
//
#include <hip/hip_runtime.h>

#define EPSV 1e-5f

// ---------------- K1: 4x4 avg-pool + GroupNorm(32) + SiLU ----------------
// grid 512 = B(16) x G(32), block 256 (one thread per pooled pixel)
__global__ __launch_bounds__(256) void k1_pool_gn1(
    const float* __restrict__ x, const float* __restrict__ g1, const float* __restrict__ b1,
    float* __restrict__ a1)
{
    const int blk = blockIdx.x;
    const int b = blk >> 5, g = blk & 31;
    const int t = threadIdx.x;
    const int ph = t >> 4, pw = t & 15;

    float v[10];
    float s = 0.f, ss = 0.f;
#pragma unroll
    for (int k = 0; k < 10; ++k) {
        const int c = g * 10 + k;
        const float* base = x + (((size_t)(b * 320 + c)) * 64 + ph * 4) * 64 + pw * 4;
        float acc = 0.f;
#pragma unroll
        for (int i = 0; i < 4; ++i) {
            const float4 r = *reinterpret_cast<const float4*>(base + i * 64);
            acc += r.x + r.y + r.z + r.w;
        }
        v[k] = acc * (1.f / 16.f);
        s += v[k];
        ss += v[k] * v[k];
    }

    __shared__ float rs[4], rss[4];
#pragma unroll
    for (int off = 32; off; off >>= 1) {
        s += __shfl_down(s, off);
        ss += __shfl_down(ss, off);
    }
    const int wid = t >> 6, lane = t & 63;
    if (lane == 0) { rs[wid] = s; rss[wid] = ss; }
    __syncthreads();
    const float S = rs[0] + rs[1] + rs[2] + rs[3];
    const float SS = rss[0] + rss[1] + rss[2] + rss[3];
    const float mean = S * (1.f / 2560.f);
    const float var = SS * (1.f / 2560.f) - mean * mean;
    const float inv = rsqrtf(var + EPSV);

#pragma unroll
    for (int k = 0; k < 10; ++k) {
        const int c = g * 10 + k;
        const float xn = (v[k] - mean) * inv * g1[c] + b1[c];
        const float y = xn / (1.f + __expf(-xn));
        a1[((size_t)(b * 320 + c)) * 256 + t] = y;
    }
}

// ---------------- K2: conv3x3 320->8 on 16x16, chunked over channels ----------------
// grid 256 = B(16) x chunks(16 of 20 channels), block 256 (one thread per pixel)
// NO atomics: each chunk writes its partial sums to a private slab z0p[b][ch][8][256].
__global__ __launch_bounds__(256) void k2_conv1(
    const float* __restrict__ a1, const float* __restrict__ w1, float* __restrict__ z0p)
{
    const int b = blockIdx.x >> 4, ch = blockIdx.x & 15;
    const int t = threadIdx.x;
    const int ph = t >> 4, pw = t & 15;
    const int c0 = ch * 20;

    __shared__ __align__(16) float tiles[20 * 256];
    __shared__ float lw[8 * 20 * 9];

    {
        const float4* src = reinterpret_cast<const float4*>(a1 + (size_t)(b * 320 + c0) * 256);
        float4* dst = reinterpret_cast<float4*>(tiles);
        for (int i = t; i < 1280; i += 256) dst[i] = src[i];
    }
    for (int i = t; i < 1440; i += 256) {
        const int o = i / 180, rem = i % 180, cc = rem / 9, k = rem % 9;
        lw[i] = w1[(o * 320 + c0 + cc) * 9 + k];
    }
    __syncthreads();

    float acc[8] = {0.f, 0.f, 0.f, 0.f, 0.f, 0.f, 0.f, 0.f};
    for (int cc = 0; cc < 20; ++cc) {
        const float* tp = &tiles[cc * 256];
#pragma unroll
        for (int ky = 0; ky < 3; ++ky) {
            const int yy = ph + ky - 1;
            if ((unsigned)yy > 15u) continue;
#pragma unroll
            for (int kx = 0; kx < 3; ++kx) {
                const int xx = pw + kx - 1;
                if ((unsigned)xx > 15u) continue;
                const float val = tp[yy * 16 + xx];
                const int wi = cc * 9 + ky * 3 + kx;
#pragma unroll
                for (int o = 0; o < 8; ++o) acc[o] += lw[o * 180 + wi] * val;
            }
        }
    }
    float* zp = z0p + (size_t)blockIdx.x * 2048 + t;   // [b][ch][o][t]
#pragma unroll
    for (int o = 0; o < 8; ++o) zp[o * 256] = acc[o];
}

// ---------------- K3A: reduce partials -> GN(8) -> per-head qkv -> attention ----------------
// grid 64 = B(16) x H(4), block 256 (one thread per pixel n).
// Each block redundantly reduces z0p and computes GN stats (cheap, L2-resident),
// projects only its head's q/k/v, and runs the full 256-key attention for (b,h)
// with k/v broadcast from LDS. Head-0 blocks also write z0 for the residual path.
__global__ __launch_bounds__(256) void k3a_attn(
    const float* __restrict__ z0p, const float* __restrict__ b_conv1,
    const float* __restrict__ ga, const float* __restrict__ ba,
    const float* __restrict__ w_qkv, const float* __restrict__ b_qkv,
    float* __restrict__ z0, float* __restrict__ aout)
{
    const int blk = blockIdx.x;
    const int b = blk >> 2, h = blk & 3;
    const int t = threadIdx.x;
    const int wid = t >> 6, lane = t & 63;

    __shared__ float zsh[8][256];
    __shared__ float stats[16];
    __shared__ float4 kvs[256];

    // reduce 16 chunk-partials + bias
    float zc[8];
#pragma unroll
    for (int c = 0; c < 8; ++c) zc[c] = b_conv1[c];
    for (int ch = 0; ch < 16; ++ch) {
        const float* pp = z0p + ((size_t)(b * 16 + ch)) * 2048 + t;
#pragma unroll
        for (int c = 0; c < 8; ++c) zc[c] += pp[c * 256];
    }
#pragma unroll
    for (int c = 0; c < 8; ++c) zsh[c][t] = zc[c];
    if (h == 0) {
#pragma unroll
        for (int c = 0; c < 8; ++c) z0[(size_t)b * 2048 + c * 256 + t] = zc[c];
    }
    __syncthreads();

    // GN(8) stats: 2 channels per wave
#pragma unroll
    for (int cc = 0; cc < 2; ++cc) {
        const int c = wid * 2 + cc;
        const float a0 = zsh[c][lane], a1v = zsh[c][lane + 64], a2v = zsh[c][lane + 128], a3v = zsh[c][lane + 192];
        float s = a0 + a1v + a2v + a3v;
        float ss = a0 * a0 + a1v * a1v + a2v * a2v + a3v * a3v;
#pragma unroll
        for (int off = 32; off; off >>= 1) {
            s += __shfl_down(s, off);
            ss += __shfl_down(ss, off);
        }
        if (lane == 0) {
            const float m = s * (1.f / 256.f);
            const float vv = ss * (1.f / 256.f) - m * m;
            stats[2 * c] = m;
            stats[2 * c + 1] = rsqrtf(vv + EPSV);
        }
    }
    __syncthreads();

    // per-head qkv: rows {2h, 2h+1} (q), {8+2h, 9+2h} (k), {16+2h, 17+2h} (v)
    float gn[8];
#pragma unroll
    for (int c = 0; c < 8; ++c) gn[c] = (zsh[c][t] - stats[2 * c]) * stats[2 * c + 1] * ga[c] + ba[c];

    float pr[6];
    const int rows[6] = {2 * h, 2 * h + 1, 8 + 2 * h, 9 + 2 * h, 16 + 2 * h, 17 + 2 * h};
#pragma unroll
    for (int j = 0; j < 6; ++j) {
        const int o = rows[j];
        float acc = b_qkv[o];
#pragma unroll
        for (int c = 0; c < 8; ++c) acc += w_qkv[o * 8 + c] * gn[c];
        pr[j] = acc;
    }
    // q pre-scaled by dh^-0.5 * log2(e) so attention inner loop is dot+exp2
    const float lscale = 0.70710678118654752f * 1.44269504088896341f;
    const float qx = pr[0] * lscale, qy = pr[1] * lscale;
    kvs[t] = make_float4(pr[2], pr[3], pr[4], pr[5]);
    __syncthreads();

    // attention (max-free softmax; scores bounded |s|<~3), uniform LDS broadcast
    float l = 0.f, o0 = 0.f, o1 = 0.f;
#pragma unroll 16
    for (int m = 0; m < 256; ++m) {
        const float4 kvv = kvs[m];
        const float e = __builtin_exp2f(qx * kvv.x + qy * kvv.y);
        l += e;
        o0 += e * kvv.z;
        o1 += e * kvv.w;
    }
    const float rl = 1.f / l;
    aout[(size_t)b * 2048 + t * 8 + 2 * h]     = o0 * rl;
    aout[(size_t)b * 2048 + t * 8 + 2 * h + 1] = o1 * rl;
}

// ---------------- K3C: proj+res, LN, MLP+res, GN2 stats (pre-upsample) + SiLU ----------------
// grid 16 = B, block 256 (one thread per pixel n)
__global__ __launch_bounds__(256) void k3c_post(
    const float* __restrict__ z0, const float* __restrict__ aout,
    const float* __restrict__ w_proj, const float* __restrict__ b_proj,
    const float* __restrict__ ln_g, const float* __restrict__ ln_b,
    const float* __restrict__ w_fc1, const float* __restrict__ b_fc1,
    const float* __restrict__ w_fc2, const float* __restrict__ b_fc2,
    const float* __restrict__ g2, const float* __restrict__ b2,
    float* __restrict__ a2)
{
    const int b = blockIdx.x, t = threadIdx.x;
    const int wid = t >> 6, lane = t & 63;

    __shared__ float zsh[8][256];
    __shared__ float stats[16];

#pragma unroll
    for (int c = 0; c < 8; ++c) zsh[c][t] = z0[(size_t)b * 2048 + c * 256 + t];

    // per-pixel attention output (8 contiguous floats)
    const float4 ao0 = *reinterpret_cast<const float4*>(aout + (size_t)b * 2048 + t * 8);
    const float4 ao1 = *reinterpret_cast<const float4*>(aout + (size_t)b * 2048 + t * 8 + 4);
    const float ao[8] = {ao0.x, ao0.y, ao0.z, ao0.w, ao1.x, ao1.y, ao1.z, ao1.w};
    __syncthreads();

    // proj + residual
    float z1[8];
#pragma unroll
    for (int o = 0; o < 8; ++o) {
        float acc = b_proj[o];
#pragma unroll
        for (int c = 0; c < 8; ++c) acc += w_proj[o * 8 + c] * ao[c];
        z1[o] = zsh[o][t] + acc;
    }

    // LayerNorm over 8 channels (per pixel)
    float mu = 0.f;
#pragma unroll
    for (int c = 0; c < 8; ++c) mu += z1[c];
    mu *= (1.f / 8.f);
    float var = 0.f;
#pragma unroll
    for (int c = 0; c < 8; ++c) { const float d = z1[c] - mu; var += d * d; }
    var *= (1.f / 8.f);
    const float linv = rsqrtf(var + EPSV);
    float ln[8];
#pragma unroll
    for (int c = 0; c < 8; ++c) ln[c] = (z1[c] - mu) * linv * ln_g[c] + ln_b[c];

    // fc1 + exact gelu
    float hg[16];
#pragma unroll
    for (int o = 0; o < 16; ++o) {
        float hv = b_fc1[o];
#pragma unroll
        for (int c = 0; c < 8; ++c) hv += w_fc1[o * 8 + c] * ln[c];
        hg[o] = 0.5f * hv * (1.f + erff(hv * 0.70710678f));
    }
    // fc2 + residual
    float z2[8];
#pragma unroll
    for (int c = 0; c < 8; ++c) {
        float acc = b_fc2[c];
#pragma unroll
        for (int o = 0; o < 16; ++o) acc += w_fc2[c * 16 + o] * hg[o];
        z2[c] = z1[c] + acc;
    }

    // GN2 stats on pre-upsample map (repeat preserves mean/var), then SiLU
    __syncthreads();
#pragma unroll
    for (int c = 0; c < 8; ++c) zsh[c][t] = z2[c];
    __syncthreads();
#pragma unroll
    for (int cc = 0; cc < 2; ++cc) {
        const int c = wid * 2 + cc;
        const float a0 = zsh[c][lane], a1v = zsh[c][lane + 64], a2v = zsh[c][lane + 128], a3v = zsh[c][lane + 192];
        float s = a0 + a1v + a2v + a3v;
        float ss = a0 * a0 + a1v * a1v + a2v * a2v + a3v * a3v;
#pragma unroll
        for (int off = 32; off; off >>= 1) {
            s += __shfl_down(s, off);
            ss += __shfl_down(ss, off);
        }
        if (lane == 0) {
            const float m = s * (1.f / 256.f);
            const float vv = ss * (1.f / 256.f) - m * m;
            stats[2 * c] = m;
            stats[2 * c + 1] = rsqrtf(vv + EPSV);
        }
    }
    __syncthreads();
#pragma unroll
    for (int c = 0; c < 8; ++c) {
        const float xn = (z2[c] - stats[2 * c]) * stats[2 * c + 1] * g2[c] + b2[c];
        a2[(size_t)b * 2048 + c * 256 + t] = xn / (1.f + __expf(-xn));
    }
}

// ---------------- K4: upsample-on-the-fly conv3x3 8->320 on 64x64 ----------------
// Upsampled input is piecewise-constant over 4x4 cells: the 16 outputs per
// cell take only 9 distinct values. ~25 FMA + ~24 adds per channel vs 144 FMA.
// grid (320, 16) = (out-channel, batch), block 256 (one thread per 4x4 cell)
__global__ __launch_bounds__(256) void k4_conv2(
    const float* __restrict__ a2, const float* __restrict__ w2,
    const float* __restrict__ bc2, float* __restrict__ out)
{
    const int o = blockIdx.x, b = blockIdx.y, t = threadIdx.x;
    __shared__ float A[8 * 324];   // (8, 18, 18) zero-halo padded pooled map
    __shared__ float wsh[72];

    for (int i = t; i < 2592; i += 256) A[i] = 0.f;
    if (t < 72) wsh[t] = w2[o * 72 + t];
    __syncthreads();
    for (int i = t; i < 2048; i += 256) {
        const int c = i >> 8, y = (i >> 4) & 15, x = i & 15;
        A[c * 324 + (y + 1) * 18 + (x + 1)] = a2[(size_t)b * 2048 + i];
    }
    __syncthreads();

    const int cy = t >> 4, cx = t & 15;
    const float bias = bc2[o];
    float acc[3][3];
#pragma unroll
    for (int r = 0; r < 3; ++r)
#pragma unroll
        for (int s = 0; s < 3; ++s) acc[r][s] = bias;

    const float* Abase = &A[cy * 18 + cx];
#pragma unroll
    for (int c = 0; c < 8; ++c) {
        const float C00 = Abase[c * 324 + 0 * 18 + 0], C01 = Abase[c * 324 + 0 * 18 + 1], C02 = Abase[c * 324 + 0 * 18 + 2];
        const float C10 = Abase[c * 324 + 1 * 18 + 0], C11 = Abase[c * 324 + 1 * 18 + 1], C12 = Abase[c * 324 + 1 * 18 + 2];
        const float C20 = Abase[c * 324 + 2 * 18 + 0], C21 = Abase[c * 324 + 2 * 18 + 1], C22 = Abase[c * 324 + 2 * 18 + 2];

        const float k0 = wsh[c * 9 + 0], k1 = wsh[c * 9 + 1], k2 = wsh[c * 9 + 2];
        const float k3 = wsh[c * 9 + 3], k4 = wsh[c * 9 + 4], k5 = wsh[c * 9 + 5];
        const float k6 = wsh[c * 9 + 6], k7 = wsh[c * 9 + 7], k8 = wsh[c * 9 + 8];

        const float q12x = k3 + k6, q12y = k4 + k7, q12z = k5 + k8;
        const float q01x = k0 + k3, q01y = k1 + k4, q01z = k2 + k5;
        const float qax = q12x + k0, qay = q12y + k1, qaz = q12z + k2;

        const float r0_c12 = k1 + k2,      r0_c012 = r0_c12 + k0,     r0_c01 = k0 + k1;
        const float q12_c12 = q12y + q12z, q12_c012 = q12_c12 + q12x, q12_c01 = q12x + q12y;
        const float qa_c12 = qay + qaz,    qa_c012 = qa_c12 + qax,    qa_c01 = qax + qay;
        const float q01_c12 = q01y + q01z, q01_c012 = q01_c12 + q01x, q01_c01 = q01x + q01y;
        const float r2_c12 = k7 + k8,      r2_c012 = r2_c12 + k6,     r2_c01 = k6 + k7;

        acc[0][0] += k0 * C00 + r0_c12 * C01 + q12x * C10 + q12_c12 * C11;
        acc[0][1] += r0_c012 * C01 + q12_c012 * C11;
        acc[0][2] += r0_c01 * C01 + k2 * C02 + q12_c01 * C11 + q12z * C12;
        acc[1][0] += qax * C10 + qa_c12 * C11;
        acc[1][1] += qa_c012 * C11;
        acc[1][2] += qa_c01 * C11 + qaz * C12;
        acc[2][0] += q01x * C10 + q01_c12 * C11 + k6 * C20 + r2_c12 * C21;
        acc[2][1] += q01_c012 * C11 + r2_c012 * C21;
        acc[2][2] += q01_c01 * C11 + q01z * C12 + r2_c01 * C21 + k8 * C22;
    }

    const size_t base = ((size_t)(b * 320 + o)) * 4096;
    const int rowmap[4] = {0, 1, 1, 2};
#pragma unroll
    for (int py = 0; py < 4; ++py) {
        const int r = rowmap[py];
        const float4 v = make_float4(acc[r][0], acc[r][1], acc[r][1], acc[r][2]);
        *reinterpret_cast<float4*>(out + base + (cy * 4 + py) * 64 + cx * 4) = v;
    }
}

extern "C" void kernel_launch(void* const* d_in, const int* in_sizes, int n_in,
                              void* d_out, int out_size, void* d_ws, size_t ws_size,
                              hipStream_t stream) {
    const float* x       = (const float*)d_in[0];
    const float* g1      = (const float*)d_in[1];
    const float* b1      = (const float*)d_in[2];
    const float* w_conv1 = (const float*)d_in[3];
    const float* b_conv1 = (const float*)d_in[4];
    const float* ga      = (const float*)d_in[5];
    const float* ba      = (const float*)d_in[6];
    const float* w_qkv   = (const float*)d_in[7];
    const float* b_qkv   = (const float*)d_in[8];
    const float* w_proj  = (const float*)d_in[9];
    const float* b_proj  = (const float*)d_in[10];
    const float* ln_g    = (const float*)d_in[11];
    const float* ln_b    = (const float*)d_in[12];
    const float* w_fc1   = (const float*)d_in[13];
    const float* b_fc1   = (const float*)d_in[14];
    const float* w_fc2   = (const float*)d_in[15];
    const float* b_fc2   = (const float*)d_in[16];
    const float* g2      = (const float*)d_in[17];
    const float* b2      = (const float*)d_in[18];
    const float* w_conv2 = (const float*)d_in[19];
    const float* b_conv2 = (const float*)d_in[20];

    float* a1   = (float*)d_ws;           // 1,310,720 floats
    float* z0p  = a1 + 1310720;           //   524,288 (16 b x 16 chunks x 2048)
    float* z0   = z0p + 524288;           //    32,768
    float* a2   = z0 + 32768;             //    32,768
    float* aout = a2 + 32768;             //    32,768
    float* out = (float*)d_out;

    k1_pool_gn1<<<512, 256, 0, stream>>>(x, g1, b1, a1);
    k2_conv1<<<256, 256, 0, stream>>>(a1, w_conv1, z0p);
    k3a_attn<<<64, 256, 0, stream>>>(z0p, b_conv1, ga, ba, w_qkv, b_qkv, z0, aout);
    k3c_post<<<16, 256, 0, stream>>>(z0, aout, w_proj, b_proj, ln_g, ln_b,
                                     w_fc1, b_fc1, w_fc2, b_fc2, g2, b2, a2);
    k4_conv2<<<dim3(320, 16), 256, 0, stream>>>(a2, w_conv2, b_conv2, out);
}

// Round 5
// 237.723 us; speedup vs baseline: 1.1400x; 1.0845x over previous
//
#include <hip/hip_runtime.h>

#define EPSV 1e-5f

// ---------------- K1: 4x4 avg-pool + GroupNorm(32) + SiLU ----------------
// grid 522 = B(16) x G(32) + 10 combo-precompute blocks, block 256
// Blocks 512..521: precompute k4's 25 combo weights per (o,c) -> cmb[320][8][25]
__global__ __launch_bounds__(256) void k1_pool_gn1(
    const float* __restrict__ x, const float* __restrict__ g1, const float* __restrict__ b1,
    float* __restrict__ a1, const float* __restrict__ w2, float* __restrict__ cmb)
{
    const int blk = blockIdx.x;
    const int t = threadIdx.x;

    if (blk >= 512) {
        // ---- combo precompute: one thread per (o,c) pair ----
        const int idx = (blk - 512) * 256 + t;          // 0..2559 = 320*8
        const float* k = w2 + idx * 9;                  // (o*8+c)*9
        const float k0 = k[0], k1 = k[1], k2 = k[2];
        const float k3 = k[3], k4 = k[4], k5 = k[5];
        const float k6 = k[6], k7 = k[7], k8 = k[8];

        const float q12x = k3 + k6, q12y = k4 + k7, q12z = k5 + k8;
        const float q01x = k0 + k3, q01y = k1 + k4, q01z = k2 + k5;
        const float qax = q12x + k0, qay = q12y + k1, qaz = q12z + k2;

        const float r0_c12 = k1 + k2,      r0_c012 = r0_c12 + k0,     r0_c01 = k0 + k1;
        const float q12_c12 = q12y + q12z, q12_c012 = q12_c12 + q12x, q12_c01 = q12x + q12y;
        const float qa_c12 = qay + qaz,    qa_c012 = qa_c12 + qax,    qa_c01 = qax + qay;
        const float q01_c12 = q01y + q01z, q01_c012 = q01_c12 + q01x, q01_c01 = q01x + q01y;
        const float r2_c12 = k7 + k8,      r2_c012 = r2_c12 + k6,     r2_c01 = k6 + k7;

        float* d = cmb + idx * 25;
        d[0] = k0;       d[1] = r0_c12;   d[2] = q12x;     d[3] = q12_c12;
        d[4] = r0_c012;  d[5] = q12_c012;
        d[6] = r0_c01;   d[7] = k2;       d[8] = q12_c01;  d[9] = q12z;
        d[10] = qax;     d[11] = qa_c12;
        d[12] = qa_c012;
        d[13] = qa_c01;  d[14] = qaz;
        d[15] = q01x;    d[16] = q01_c12; d[17] = k6;      d[18] = r2_c12;
        d[19] = q01_c012; d[20] = r2_c012;
        d[21] = q01_c01; d[22] = q01z;    d[23] = r2_c01;  d[24] = k8;
        return;
    }

    const int b = blk >> 5, g = blk & 31;
    const int ph = t >> 4, pw = t & 15;

    float v[10];
    float s = 0.f, ss = 0.f;
#pragma unroll
    for (int k = 0; k < 10; ++k) {
        const int c = g * 10 + k;
        const float* base = x + (((size_t)(b * 320 + c)) * 64 + ph * 4) * 64 + pw * 4;
        float acc = 0.f;
#pragma unroll
        for (int i = 0; i < 4; ++i) {
            const float4 r = *reinterpret_cast<const float4*>(base + i * 64);
            acc += r.x + r.y + r.z + r.w;
        }
        v[k] = acc * (1.f / 16.f);
        s += v[k];
        ss += v[k] * v[k];
    }

    __shared__ float rs[4], rss[4];
#pragma unroll
    for (int off = 32; off; off >>= 1) {
        s += __shfl_down(s, off);
        ss += __shfl_down(ss, off);
    }
    const int wid = t >> 6, lane = t & 63;
    if (lane == 0) { rs[wid] = s; rss[wid] = ss; }
    __syncthreads();
    const float S = rs[0] + rs[1] + rs[2] + rs[3];
    const float SS = rss[0] + rss[1] + rss[2] + rss[3];
    const float mean = S * (1.f / 2560.f);
    const float var = SS * (1.f / 2560.f) - mean * mean;
    const float inv = rsqrtf(var + EPSV);

#pragma unroll
    for (int k = 0; k < 10; ++k) {
        const int c = g * 10 + k;
        const float xn = (v[k] - mean) * inv * g1[c] + b1[c];
        const float y = xn / (1.f + __expf(-xn));
        a1[((size_t)(b * 320 + c)) * 256 + t] = y;
    }
}

// ---------------- K2: conv3x3 320->8 on 16x16, chunked over channels ----------------
// grid 256 = B(16) x chunks(16 of 20 channels), block 256 (one thread per pixel)
// NO atomics: each chunk writes its partial sums to a private slab z0p[b][ch][8][256].
__global__ __launch_bounds__(256) void k2_conv1(
    const float* __restrict__ a1, const float* __restrict__ w1, float* __restrict__ z0p)
{
    const int b = blockIdx.x >> 4, ch = blockIdx.x & 15;
    const int t = threadIdx.x;
    const int ph = t >> 4, pw = t & 15;
    const int c0 = ch * 20;

    __shared__ __align__(16) float tiles[20 * 256];
    __shared__ float lw[8 * 20 * 9];

    {
        const float4* src = reinterpret_cast<const float4*>(a1 + (size_t)(b * 320 + c0) * 256);
        float4* dst = reinterpret_cast<float4*>(tiles);
        for (int i = t; i < 1280; i += 256) dst[i] = src[i];
    }
    for (int i = t; i < 1440; i += 256) {
        const int o = i / 180, rem = i % 180, cc = rem / 9, k = rem % 9;
        lw[i] = w1[(o * 320 + c0 + cc) * 9 + k];
    }
    __syncthreads();

    float acc[8] = {0.f, 0.f, 0.f, 0.f, 0.f, 0.f, 0.f, 0.f};
    for (int cc = 0; cc < 20; ++cc) {
        const float* tp = &tiles[cc * 256];
#pragma unroll
        for (int ky = 0; ky < 3; ++ky) {
            const int yy = ph + ky - 1;
            if ((unsigned)yy > 15u) continue;
#pragma unroll
            for (int kx = 0; kx < 3; ++kx) {
                const int xx = pw + kx - 1;
                if ((unsigned)xx > 15u) continue;
                const float val = tp[yy * 16 + xx];
                const int wi = cc * 9 + ky * 3 + kx;
#pragma unroll
                for (int o = 0; o < 8; ++o) acc[o] += lw[o * 180 + wi] * val;
            }
        }
    }
    float* zp = z0p + (size_t)blockIdx.x * 2048 + t;   // [b][ch][o][t]
#pragma unroll
    for (int o = 0; o < 8; ++o) zp[o * 256] = acc[o];
}

// ---------------- K3A: reduce partials -> GN(8) -> per-head qkv -> attention ----------------
// grid 64 = B(16) x H(4), block 256 (one thread per pixel n).
__global__ __launch_bounds__(256) void k3a_attn(
    const float* __restrict__ z0p, const float* __restrict__ b_conv1,
    const float* __restrict__ ga, const float* __restrict__ ba,
    const float* __restrict__ w_qkv, const float* __restrict__ b_qkv,
    float* __restrict__ z0, float* __restrict__ aout)
{
    const int blk = blockIdx.x;
    const int b = blk >> 2, h = blk & 3;
    const int t = threadIdx.x;
    const int wid = t >> 6, lane = t & 63;

    __shared__ float zsh[8][256];
    __shared__ float stats[16];
    __shared__ float4 kvs[256];

    // reduce 16 chunk-partials + bias
    float zc[8];
#pragma unroll
    for (int c = 0; c < 8; ++c) zc[c] = b_conv1[c];
    for (int ch = 0; ch < 16; ++ch) {
        const float* pp = z0p + ((size_t)(b * 16 + ch)) * 2048 + t;
#pragma unroll
        for (int c = 0; c < 8; ++c) zc[c] += pp[c * 256];
    }
#pragma unroll
    for (int c = 0; c < 8; ++c) zsh[c][t] = zc[c];
    if (h == 0) {
#pragma unroll
        for (int c = 0; c < 8; ++c) z0[(size_t)b * 2048 + c * 256 + t] = zc[c];
    }
    __syncthreads();

    // GN(8) stats: 2 channels per wave
#pragma unroll
    for (int cc = 0; cc < 2; ++cc) {
        const int c = wid * 2 + cc;
        const float a0 = zsh[c][lane], a1v = zsh[c][lane + 64], a2v = zsh[c][lane + 128], a3v = zsh[c][lane + 192];
        float s = a0 + a1v + a2v + a3v;
        float ss = a0 * a0 + a1v * a1v + a2v * a2v + a3v * a3v;
#pragma unroll
        for (int off = 32; off; off >>= 1) {
            s += __shfl_down(s, off);
            ss += __shfl_down(ss, off);
        }
        if (lane == 0) {
            const float m = s * (1.f / 256.f);
            const float vv = ss * (1.f / 256.f) - m * m;
            stats[2 * c] = m;
            stats[2 * c + 1] = rsqrtf(vv + EPSV);
        }
    }
    __syncthreads();

    // per-head qkv: rows {2h, 2h+1} (q), {8+2h, 9+2h} (k), {16+2h, 17+2h} (v)
    float gn[8];
#pragma unroll
    for (int c = 0; c < 8; ++c) gn[c] = (zsh[c][t] - stats[2 * c]) * stats[2 * c + 1] * ga[c] + ba[c];

    float pr[6];
    const int rows[6] = {2 * h, 2 * h + 1, 8 + 2 * h, 9 + 2 * h, 16 + 2 * h, 17 + 2 * h};
#pragma unroll
    for (int j = 0; j < 6; ++j) {
        const int o = rows[j];
        float acc = b_qkv[o];
#pragma unroll
        for (int c = 0; c < 8; ++c) acc += w_qkv[o * 8 + c] * gn[c];
        pr[j] = acc;
    }
    // q pre-scaled by dh^-0.5 * log2(e) so attention inner loop is dot+exp2
    const float lscale = 0.70710678118654752f * 1.44269504088896341f;
    const float qx = pr[0] * lscale, qy = pr[1] * lscale;
    kvs[t] = make_float4(pr[2], pr[3], pr[4], pr[5]);
    __syncthreads();

    // attention (max-free softmax; scores bounded |s|<~3), uniform LDS broadcast
    float l = 0.f, o0 = 0.f, o1 = 0.f;
#pragma unroll 16
    for (int m = 0; m < 256; ++m) {
        const float4 kvv = kvs[m];
        const float e = __builtin_exp2f(qx * kvv.x + qy * kvv.y);
        l += e;
        o0 += e * kvv.z;
        o1 += e * kvv.w;
    }
    const float rl = 1.f / l;
    aout[(size_t)b * 2048 + t * 8 + 2 * h]     = o0 * rl;
    aout[(size_t)b * 2048 + t * 8 + 2 * h + 1] = o1 * rl;
}

// ---------------- K3C: proj+res, LN, MLP+res, GN2 stats (pre-upsample) + SiLU ----------------
// grid 16 = B, block 256 (one thread per pixel n)
__global__ __launch_bounds__(256) void k3c_post(
    const float* __restrict__ z0, const float* __restrict__ aout,
    const float* __restrict__ w_proj, const float* __restrict__ b_proj,
    const float* __restrict__ ln_g, const float* __restrict__ ln_b,
    const float* __restrict__ w_fc1, const float* __restrict__ b_fc1,
    const float* __restrict__ w_fc2, const float* __restrict__ b_fc2,
    const float* __restrict__ g2, const float* __restrict__ b2,
    float* __restrict__ a2)
{
    const int b = blockIdx.x, t = threadIdx.x;
    const int wid = t >> 6, lane = t & 63;

    __shared__ float zsh[8][256];
    __shared__ float stats[16];

#pragma unroll
    for (int c = 0; c < 8; ++c) zsh[c][t] = z0[(size_t)b * 2048 + c * 256 + t];

    // per-pixel attention output (8 contiguous floats)
    const float4 ao0 = *reinterpret_cast<const float4*>(aout + (size_t)b * 2048 + t * 8);
    const float4 ao1 = *reinterpret_cast<const float4*>(aout + (size_t)b * 2048 + t * 8 + 4);
    const float ao[8] = {ao0.x, ao0.y, ao0.z, ao0.w, ao1.x, ao1.y, ao1.z, ao1.w};
    __syncthreads();

    // proj + residual
    float z1[8];
#pragma unroll
    for (int o = 0; o < 8; ++o) {
        float acc = b_proj[o];
#pragma unroll
        for (int c = 0; c < 8; ++c) acc += w_proj[o * 8 + c] * ao[c];
        z1[o] = zsh[o][t] + acc;
    }

    // LayerNorm over 8 channels (per pixel)
    float mu = 0.f;
#pragma unroll
    for (int c = 0; c < 8; ++c) mu += z1[c];
    mu *= (1.f / 8.f);
    float var = 0.f;
#pragma unroll
    for (int c = 0; c < 8; ++c) { const float d = z1[c] - mu; var += d * d; }
    var *= (1.f / 8.f);
    const float linv = rsqrtf(var + EPSV);
    float ln[8];
#pragma unroll
    for (int c = 0; c < 8; ++c) ln[c] = (z1[c] - mu) * linv * ln_g[c] + ln_b[c];

    // fc1 + exact gelu
    float hg[16];
#pragma unroll
    for (int o = 0; o < 16; ++o) {
        float hv = b_fc1[o];
#pragma unroll
        for (int c = 0; c < 8; ++c) hv += w_fc1[o * 8 + c] * ln[c];
        hg[o] = 0.5f * hv * (1.f + erff(hv * 0.70710678f));
    }
    // fc2 + residual
    float z2[8];
#pragma unroll
    for (int c = 0; c < 8; ++c) {
        float acc = b_fc2[c];
#pragma unroll
        for (int o = 0; o < 16; ++o) acc += w_fc2[c * 16 + o] * hg[o];
        z2[c] = z1[c] + acc;
    }

    // GN2 stats on pre-upsample map (repeat preserves mean/var), then SiLU
    __syncthreads();
#pragma unroll
    for (int c = 0; c < 8; ++c) zsh[c][t] = z2[c];
    __syncthreads();
#pragma unroll
    for (int cc = 0; cc < 2; ++cc) {
        const int c = wid * 2 + cc;
        const float a0 = zsh[c][lane], a1v = zsh[c][lane + 64], a2v = zsh[c][lane + 128], a3v = zsh[c][lane + 192];
        float s = a0 + a1v + a2v + a3v;
        float ss = a0 * a0 + a1v * a1v + a2v * a2v + a3v * a3v;
#pragma unroll
        for (int off = 32; off; off >>= 1) {
            s += __shfl_down(s, off);
            ss += __shfl_down(ss, off);
        }
        if (lane == 0) {
            const float m = s * (1.f / 256.f);
            const float vv = ss * (1.f / 256.f) - m * m;
            stats[2 * c] = m;
            stats[2 * c + 1] = rsqrtf(vv + EPSV);
        }
    }
    __syncthreads();
#pragma unroll
    for (int c = 0; c < 8; ++c) {
        const float xn = (z2[c] - stats[2 * c]) * stats[2 * c + 1] * g2[c] + b2[c];
        a2[(size_t)b * 2048 + c * 256 + t] = xn / (1.f + __expf(-xn));
    }
}

// ---------------- K4: upsample-on-the-fly conv3x3 8->320 on 64x64 ----------------
// Combo weights precomputed per (o,c) in k1's tail blocks; read here via
// block-uniform addresses -> s_load into SGPRs. Inner loop: 25 v_fmac with
// SGPR weight operand + 9 LDS cell reads per channel.
// grid (320, 16) = (out-channel, batch), block 256 (one thread per 4x4 cell)
__global__ __launch_bounds__(256) void k4_conv2(
    const float* __restrict__ a2, const float* __restrict__ cmb,
    const float* __restrict__ bc2, float* __restrict__ out)
{
    const int o = blockIdx.x, b = blockIdx.y, t = threadIdx.x;
    __shared__ float A[8 * 324];   // (8, 18, 18) zero-halo padded pooled map

    // zero only the 68-cell halo ring per channel (interior fully overwritten)
    for (int i = t; i < 544; i += 256) {
        const int c = i / 68, r = i % 68;
        int y, xx;
        if (r < 18)      { y = 0;      xx = r; }
        else if (r < 36) { y = 17;     xx = r - 18; }
        else if (r < 52) { y = r - 35; xx = 0; }
        else             { y = r - 51; xx = 17; }
        A[c * 324 + y * 18 + xx] = 0.f;
    }
    for (int i = t; i < 2048; i += 256) {
        const int c = i >> 8, y = (i >> 4) & 15, xx = i & 15;
        A[c * 324 + (y + 1) * 18 + (xx + 1)] = a2[(size_t)b * 2048 + i];
    }
    __syncthreads();

    const int cy = t >> 4, cx = t & 15;
    const float bias = bc2[o];
    float acc[3][3];
#pragma unroll
    for (int r = 0; r < 3; ++r)
#pragma unroll
        for (int s = 0; s < 3; ++s) acc[r][s] = bias;

    const float* wp = cmb + o * 200;       // block-uniform -> SGPR
    const float* Abase = &A[cy * 18 + cx];
#pragma unroll
    for (int c = 0; c < 8; ++c) {
        const float C00 = Abase[c * 324 + 0],  C01 = Abase[c * 324 + 1],  C02 = Abase[c * 324 + 2];
        const float C10 = Abase[c * 324 + 18], C11 = Abase[c * 324 + 19], C12 = Abase[c * 324 + 20];
        const float C20 = Abase[c * 324 + 36], C21 = Abase[c * 324 + 37], C22 = Abase[c * 324 + 38];
        const float* w = wp + c * 25;

        acc[0][0] += w[0] * C00 + w[1] * C01 + w[2] * C10 + w[3] * C11;
        acc[0][1] += w[4] * C01 + w[5] * C11;
        acc[0][2] += w[6] * C01 + w[7] * C02 + w[8] * C11 + w[9] * C12;
        acc[1][0] += w[10] * C10 + w[11] * C11;
        acc[1][1] += w[12] * C11;
        acc[1][2] += w[13] * C11 + w[14] * C12;
        acc[2][0] += w[15] * C10 + w[16] * C11 + w[17] * C20 + w[18] * C21;
        acc[2][1] += w[19] * C11 + w[20] * C21;
        acc[2][2] += w[21] * C11 + w[22] * C12 + w[23] * C21 + w[24] * C22;
    }

    const size_t base = ((size_t)(b * 320 + o)) * 4096;
    const int rowmap[4] = {0, 1, 1, 2};
#pragma unroll
    for (int py = 0; py < 4; ++py) {
        const int r = rowmap[py];
        const float4 v = make_float4(acc[r][0], acc[r][1], acc[r][1], acc[r][2]);
        *reinterpret_cast<float4*>(out + base + (cy * 4 + py) * 64 + cx * 4) = v;
    }
}

extern "C" void kernel_launch(void* const* d_in, const int* in_sizes, int n_in,
                              void* d_out, int out_size, void* d_ws, size_t ws_size,
                              hipStream_t stream) {
    const float* x       = (const float*)d_in[0];
    const float* g1      = (const float*)d_in[1];
    const float* b1      = (const float*)d_in[2];
    const float* w_conv1 = (const float*)d_in[3];
    const float* b_conv1 = (const float*)d_in[4];
    const float* ga      = (const float*)d_in[5];
    const float* ba      = (const float*)d_in[6];
    const float* w_qkv   = (const float*)d_in[7];
    const float* b_qkv   = (const float*)d_in[8];
    const float* w_proj  = (const float*)d_in[9];
    const float* b_proj  = (const float*)d_in[10];
    const float* ln_g    = (const float*)d_in[11];
    const float* ln_b    = (const float*)d_in[12];
    const float* w_fc1   = (const float*)d_in[13];
    const float* b_fc1   = (const float*)d_in[14];
    const float* w_fc2   = (const float*)d_in[15];
    const float* b_fc2   = (const float*)d_in[16];
    const float* g2      = (const float*)d_in[17];
    const float* b2      = (const float*)d_in[18];
    const float* w_conv2 = (const float*)d_in[19];
    const float* b_conv2 = (const float*)d_in[20];

    float* a1   = (float*)d_ws;           // 1,310,720 floats
    float* z0p  = a1 + 1310720;           //   524,288 (16 b x 16 chunks x 2048)
    float* z0   = z0p + 524288;           //    32,768
    float* a2   = z0 + 32768;             //    32,768
    float* aout = a2 + 32768;             //    32,768
    float* cmb  = aout + 32768;           //    64,000 (320 o x 8 c x 25 combos)
    float* out = (float*)d_out;

    k1_pool_gn1<<<522, 256, 0, stream>>>(x, g1, b1, a1, w_conv2, cmb);
    k2_conv1<<<256, 256, 0, stream>>>(a1, w_conv1, z0p);
    k3a_attn<<<64, 256, 0, stream>>>(z0p, b_conv1, ga, ba, w_qkv, b_qkv, z0, aout);
    k3c_post<<<16, 256, 0, stream>>>(z0, aout, w_proj, b_proj, ln_g, ln_b,
                                     w_fc1, b_fc1, w_fc2, b_fc2, g2, b2, a2);
    k4_conv2<<<dim3(320, 16), 256, 0, stream>>>(a2, cmb, b_conv2, out);
}

// Round 6
// 236.470 us; speedup vs baseline: 1.1461x; 1.0053x over previous
//
#include <hip/hip_runtime.h>

#define EPSV 1e-5f

// ---------------- K12: 4x4 avg-pool + GroupNorm(32) + SiLU + conv3x3 320->8 (chunked) ----------------
// grid 266 = B(16) x chunks(16) + 10 combo-precompute blocks, block 256.
// A chunk of 20 channels = exactly 2 complete GN groups (group g = channels
// 10g..10g+9), so stats are computed entirely in-block, bit-identically to the
// old K1 (same per-thread summation order, same wave reduction). Pooled+SiLU
// values go straight to the conv LDS tile -- the a1 intermediate is gone.
// Each chunk-block writes conv partials to z0p[b][ch][8][256] (no atomics).
__global__ __launch_bounds__(256) void k12_pool_gn_conv(
    const float* __restrict__ x, const float* __restrict__ g1, const float* __restrict__ b1,
    const float* __restrict__ w1, float* __restrict__ z0p,
    const float* __restrict__ w2, float* __restrict__ cmb)
{
    const int blk = blockIdx.x;
    const int t = threadIdx.x;

    if (blk >= 256) {
        // ---- combo precompute for k4: one thread per (o,c) pair ----
        const int idx = (blk - 256) * 256 + t;          // 0..2559 = 320*8
        const float* k = w2 + idx * 9;                  // (o*8+c)*9
        const float k0 = k[0], k1 = k[1], k2 = k[2];
        const float k3 = k[3], k4 = k[4], k5 = k[5];
        const float k6 = k[6], k7 = k[7], k8 = k[8];

        const float q12x = k3 + k6, q12y = k4 + k7, q12z = k5 + k8;
        const float q01x = k0 + k3, q01y = k1 + k4, q01z = k2 + k5;
        const float qax = q12x + k0, qay = q12y + k1, qaz = q12z + k2;

        const float r0_c12 = k1 + k2,      r0_c012 = r0_c12 + k0,     r0_c01 = k0 + k1;
        const float q12_c12 = q12y + q12z, q12_c012 = q12_c12 + q12x, q12_c01 = q12x + q12y;
        const float qa_c12 = qay + qaz,    qa_c012 = qa_c12 + qax,    qa_c01 = qax + qay;
        const float q01_c12 = q01y + q01z, q01_c012 = q01_c12 + q01x, q01_c01 = q01x + q01y;
        const float r2_c12 = k7 + k8,      r2_c012 = r2_c12 + k6,     r2_c01 = k6 + k7;

        float* d = cmb + idx * 25;
        d[0] = k0;        d[1] = r0_c12;   d[2] = q12x;     d[3] = q12_c12;
        d[4] = r0_c012;   d[5] = q12_c012;
        d[6] = r0_c01;    d[7] = k2;       d[8] = q12_c01;  d[9] = q12z;
        d[10] = qax;      d[11] = qa_c12;
        d[12] = qa_c012;
        d[13] = qa_c01;   d[14] = qaz;
        d[15] = q01x;     d[16] = q01_c12; d[17] = k6;      d[18] = r2_c12;
        d[19] = q01_c012; d[20] = r2_c012;
        d[21] = q01_c01;  d[22] = q01z;    d[23] = r2_c01;  d[24] = k8;
        return;
    }

    const int b = blk >> 4, ch = blk & 15;
    const int ph = t >> 4, pw = t & 15;
    const int c0 = ch * 20;
    const int wid = t >> 6, lane = t & 63;

    __shared__ __align__(16) float tiles[20 * 256];
    __shared__ float lw[8 * 20 * 9];
    __shared__ float rs[2][4], rss[2][4];

    // conv weights for this chunk (overlaps with pooling loads)
    for (int i = t; i < 1440; i += 256) {
        const int o = i / 180, rem = i % 180, cc = rem / 9, k = rem % 9;
        lw[i] = w1[(o * 320 + c0 + cc) * 9 + k];
    }

    // pool 20 channels; accumulate per-group stats (groups 2ch, 2ch+1)
    float v[20];
    float s[2] = {0.f, 0.f}, ss[2] = {0.f, 0.f};
#pragma unroll
    for (int k = 0; k < 20; ++k) {
        const int c = c0 + k;
        const float* base = x + (((size_t)(b * 320 + c)) * 64 + ph * 4) * 64 + pw * 4;
        float acc = 0.f;
#pragma unroll
        for (int i = 0; i < 4; ++i) {
            const float4 r = *reinterpret_cast<const float4*>(base + i * 64);
            acc += r.x + r.y + r.z + r.w;
        }
        v[k] = acc * (1.f / 16.f);
        const int g = k / 10;
        s[g] += v[k];
        ss[g] += v[k] * v[k];
    }

#pragma unroll
    for (int off = 32; off; off >>= 1) {
#pragma unroll
        for (int g = 0; g < 2; ++g) {
            s[g] += __shfl_down(s[g], off);
            ss[g] += __shfl_down(ss[g], off);
        }
    }
    if (lane == 0) {
#pragma unroll
        for (int g = 0; g < 2; ++g) { rs[g][wid] = s[g]; rss[g][wid] = ss[g]; }
    }
    __syncthreads();

    float mean[2], inv[2];
#pragma unroll
    for (int g = 0; g < 2; ++g) {
        const float S = rs[g][0] + rs[g][1] + rs[g][2] + rs[g][3];
        const float SS = rss[g][0] + rss[g][1] + rss[g][2] + rss[g][3];
        mean[g] = S * (1.f / 2560.f);
        const float var = SS * (1.f / 2560.f) - mean[g] * mean[g];
        inv[g] = rsqrtf(var + EPSV);
    }

    // GN + SiLU straight into the conv tile (no global intermediate)
#pragma unroll
    for (int k = 0; k < 20; ++k) {
        const int c = c0 + k, g = k / 10;
        const float xn = (v[k] - mean[g]) * inv[g] * g1[c] + b1[c];
        tiles[k * 256 + t] = xn / (1.f + __expf(-xn));
    }
    __syncthreads();

    // conv3x3 over the 20 staged channels
    float acc[8] = {0.f, 0.f, 0.f, 0.f, 0.f, 0.f, 0.f, 0.f};
    for (int cc = 0; cc < 20; ++cc) {
        const float* tp = &tiles[cc * 256];
#pragma unroll
        for (int ky = 0; ky < 3; ++ky) {
            const int yy = ph + ky - 1;
            if ((unsigned)yy > 15u) continue;
#pragma unroll
            for (int kx = 0; kx < 3; ++kx) {
                const int xx = pw + kx - 1;
                if ((unsigned)xx > 15u) continue;
                const float val = tp[yy * 16 + xx];
                const int wi = cc * 9 + ky * 3 + kx;
#pragma unroll
                for (int o = 0; o < 8; ++o) acc[o] += lw[o * 180 + wi] * val;
            }
        }
    }
    float* zp = z0p + (size_t)blk * 2048 + t;   // [b][ch][o][t]
#pragma unroll
    for (int o = 0; o < 8; ++o) zp[o * 256] = acc[o];
}

// ---------------- K3A: reduce partials -> GN(8) -> per-head qkv -> attention ----------------
// grid 64 = B(16) x H(4), block 256 (one thread per pixel n).
__global__ __launch_bounds__(256) void k3a_attn(
    const float* __restrict__ z0p, const float* __restrict__ b_conv1,
    const float* __restrict__ ga, const float* __restrict__ ba,
    const float* __restrict__ w_qkv, const float* __restrict__ b_qkv,
    float* __restrict__ z0, float* __restrict__ aout)
{
    const int blk = blockIdx.x;
    const int b = blk >> 2, h = blk & 3;
    const int t = threadIdx.x;
    const int wid = t >> 6, lane = t & 63;

    __shared__ float zsh[8][256];
    __shared__ float stats[16];
    __shared__ float4 kvs[256];

    // reduce 16 chunk-partials + bias
    float zc[8];
#pragma unroll
    for (int c = 0; c < 8; ++c) zc[c] = b_conv1[c];
    for (int ch = 0; ch < 16; ++ch) {
        const float* pp = z0p + ((size_t)(b * 16 + ch)) * 2048 + t;
#pragma unroll
        for (int c = 0; c < 8; ++c) zc[c] += pp[c * 256];
    }
#pragma unroll
    for (int c = 0; c < 8; ++c) zsh[c][t] = zc[c];
    if (h == 0) {
#pragma unroll
        for (int c = 0; c < 8; ++c) z0[(size_t)b * 2048 + c * 256 + t] = zc[c];
    }
    __syncthreads();

    // GN(8) stats: 2 channels per wave
#pragma unroll
    for (int cc = 0; cc < 2; ++cc) {
        const int c = wid * 2 + cc;
        const float a0 = zsh[c][lane], a1v = zsh[c][lane + 64], a2v = zsh[c][lane + 128], a3v = zsh[c][lane + 192];
        float s = a0 + a1v + a2v + a3v;
        float ss = a0 * a0 + a1v * a1v + a2v * a2v + a3v * a3v;
#pragma unroll
        for (int off = 32; off; off >>= 1) {
            s += __shfl_down(s, off);
            ss += __shfl_down(ss, off);
        }
        if (lane == 0) {
            const float m = s * (1.f / 256.f);
            const float vv = ss * (1.f / 256.f) - m * m;
            stats[2 * c] = m;
            stats[2 * c + 1] = rsqrtf(vv + EPSV);
        }
    }
    __syncthreads();

    // per-head qkv: rows {2h, 2h+1} (q), {8+2h, 9+2h} (k), {16+2h, 17+2h} (v)
    float gn[8];
#pragma unroll
    for (int c = 0; c < 8; ++c) gn[c] = (zsh[c][t] - stats[2 * c]) * stats[2 * c + 1] * ga[c] + ba[c];

    float pr[6];
    const int rows[6] = {2 * h, 2 * h + 1, 8 + 2 * h, 9 + 2 * h, 16 + 2 * h, 17 + 2 * h};
#pragma unroll
    for (int j = 0; j < 6; ++j) {
        const int o = rows[j];
        float acc = b_qkv[o];
#pragma unroll
        for (int c = 0; c < 8; ++c) acc += w_qkv[o * 8 + c] * gn[c];
        pr[j] = acc;
    }
    // q pre-scaled by dh^-0.5 * log2(e) so attention inner loop is dot+exp2
    const float lscale = 0.70710678118654752f * 1.44269504088896341f;
    const float qx = pr[0] * lscale, qy = pr[1] * lscale;
    kvs[t] = make_float4(pr[2], pr[3], pr[4], pr[5]);
    __syncthreads();

    // attention (max-free softmax; scores bounded |s|<~3), uniform LDS broadcast
    float l = 0.f, o0 = 0.f, o1 = 0.f;
#pragma unroll 16
    for (int m = 0; m < 256; ++m) {
        const float4 kvv = kvs[m];
        const float e = __builtin_exp2f(qx * kvv.x + qy * kvv.y);
        l += e;
        o0 += e * kvv.z;
        o1 += e * kvv.w;
    }
    const float rl = 1.f / l;
    aout[(size_t)b * 2048 + t * 8 + 2 * h]     = o0 * rl;
    aout[(size_t)b * 2048 + t * 8 + 2 * h + 1] = o1 * rl;
}

// ---------------- K3C: proj+res, LN, MLP+res, GN2 stats (pre-upsample) + SiLU ----------------
// grid 16 = B, block 256 (one thread per pixel n)
__global__ __launch_bounds__(256) void k3c_post(
    const float* __restrict__ z0, const float* __restrict__ aout,
    const float* __restrict__ w_proj, const float* __restrict__ b_proj,
    const float* __restrict__ ln_g, const float* __restrict__ ln_b,
    const float* __restrict__ w_fc1, const float* __restrict__ b_fc1,
    const float* __restrict__ w_fc2, const float* __restrict__ b_fc2,
    const float* __restrict__ g2, const float* __restrict__ b2,
    float* __restrict__ a2)
{
    const int b = blockIdx.x, t = threadIdx.x;
    const int wid = t >> 6, lane = t & 63;

    __shared__ float zsh[8][256];
    __shared__ float stats[16];

#pragma unroll
    for (int c = 0; c < 8; ++c) zsh[c][t] = z0[(size_t)b * 2048 + c * 256 + t];

    // per-pixel attention output (8 contiguous floats)
    const float4 ao0 = *reinterpret_cast<const float4*>(aout + (size_t)b * 2048 + t * 8);
    const float4 ao1 = *reinterpret_cast<const float4*>(aout + (size_t)b * 2048 + t * 8 + 4);
    const float ao[8] = {ao0.x, ao0.y, ao0.z, ao0.w, ao1.x, ao1.y, ao1.z, ao1.w};
    __syncthreads();

    // proj + residual
    float z1[8];
#pragma unroll
    for (int o = 0; o < 8; ++o) {
        float acc = b_proj[o];
#pragma unroll
        for (int c = 0; c < 8; ++c) acc += w_proj[o * 8 + c] * ao[c];
        z1[o] = zsh[o][t] + acc;
    }

    // LayerNorm over 8 channels (per pixel)
    float mu = 0.f;
#pragma unroll
    for (int c = 0; c < 8; ++c) mu += z1[c];
    mu *= (1.f / 8.f);
    float var = 0.f;
#pragma unroll
    for (int c = 0; c < 8; ++c) { const float d = z1[c] - mu; var += d * d; }
    var *= (1.f / 8.f);
    const float linv = rsqrtf(var + EPSV);
    float ln[8];
#pragma unroll
    for (int c = 0; c < 8; ++c) ln[c] = (z1[c] - mu) * linv * ln_g[c] + ln_b[c];

    // fc1 + exact gelu
    float hg[16];
#pragma unroll
    for (int o = 0; o < 16; ++o) {
        float hv = b_fc1[o];
#pragma unroll
        for (int c = 0; c < 8; ++c) hv += w_fc1[o * 8 + c] * ln[c];
        hg[o] = 0.5f * hv * (1.f + erff(hv * 0.70710678f));
    }
    // fc2 + residual
    float z2[8];
#pragma unroll
    for (int c = 0; c < 8; ++c) {
        float acc = b_fc2[c];
#pragma unroll
        for (int o = 0; o < 16; ++o) acc += w_fc2[c * 16 + o] * hg[o];
        z2[c] = z1[c] + acc;
    }

    // GN2 stats on pre-upsample map (repeat preserves mean/var), then SiLU
    __syncthreads();
#pragma unroll
    for (int c = 0; c < 8; ++c) zsh[c][t] = z2[c];
    __syncthreads();
#pragma unroll
    for (int cc = 0; cc < 2; ++cc) {
        const int c = wid * 2 + cc;
        const float a0 = zsh[c][lane], a1v = zsh[c][lane + 64], a2v = zsh[c][lane + 128], a3v = zsh[c][lane + 192];
        float s = a0 + a1v + a2v + a3v;
        float ss = a0 * a0 + a1v * a1v + a2v * a2v + a3v * a3v;
#pragma unroll
        for (int off = 32; off; off >>= 1) {
            s += __shfl_down(s, off);
            ss += __shfl_down(ss, off);
        }
        if (lane == 0) {
            const float m = s * (1.f / 256.f);
            const float vv = ss * (1.f / 256.f) - m * m;
            stats[2 * c] = m;
            stats[2 * c + 1] = rsqrtf(vv + EPSV);
        }
    }
    __syncthreads();
#pragma unroll
    for (int c = 0; c < 8; ++c) {
        const float xn = (z2[c] - stats[2 * c]) * stats[2 * c + 1] * g2[c] + b2[c];
        a2[(size_t)b * 2048 + c * 256 + t] = xn / (1.f + __expf(-xn));
    }
}

// ---------------- K4: upsample-on-the-fly conv3x3 8->320 on 64x64 ----------------
// Combo weights precomputed per (o,c) in k12's tail blocks; read here via
// block-uniform addresses -> s_load into SGPRs. Inner loop: 25 v_fmac with
// SGPR weight operand + 9 LDS cell reads per channel.
// grid (320, 16) = (out-channel, batch), block 256 (one thread per 4x4 cell)
__global__ __launch_bounds__(256) void k4_conv2(
    const float* __restrict__ a2, const float* __restrict__ cmb,
    const float* __restrict__ bc2, float* __restrict__ out)
{
    const int o = blockIdx.x, b = blockIdx.y, t = threadIdx.x;
    __shared__ float A[8 * 324];   // (8, 18, 18) zero-halo padded pooled map

    // zero only the 68-cell halo ring per channel (interior fully overwritten)
    for (int i = t; i < 544; i += 256) {
        const int c = i / 68, r = i % 68;
        int y, xx;
        if (r < 18)      { y = 0;      xx = r; }
        else if (r < 36) { y = 17;     xx = r - 18; }
        else if (r < 52) { y = r - 35; xx = 0; }
        else             { y = r - 51; xx = 17; }
        A[c * 324 + y * 18 + xx] = 0.f;
    }
    for (int i = t; i < 2048; i += 256) {
        const int c = i >> 8, y = (i >> 4) & 15, xx = i & 15;
        A[c * 324 + (y + 1) * 18 + (xx + 1)] = a2[(size_t)b * 2048 + i];
    }
    __syncthreads();

    const int cy = t >> 4, cx = t & 15;
    const float bias = bc2[o];
    float acc[3][3];
#pragma unroll
    for (int r = 0; r < 3; ++r)
#pragma unroll
        for (int s = 0; s < 3; ++s) acc[r][s] = bias;

    const float* wp = cmb + o * 200;       // block-uniform -> SGPR
    const float* Abase = &A[cy * 18 + cx];
#pragma unroll
    for (int c = 0; c < 8; ++c) {
        const float C00 = Abase[c * 324 + 0],  C01 = Abase[c * 324 + 1],  C02 = Abase[c * 324 + 2];
        const float C10 = Abase[c * 324 + 18], C11 = Abase[c * 324 + 19], C12 = Abase[c * 324 + 20];
        const float C20 = Abase[c * 324 + 36], C21 = Abase[c * 324 + 37], C22 = Abase[c * 324 + 38];
        const float* w = wp + c * 25;

        acc[0][0] += w[0] * C00 + w[1] * C01 + w[2] * C10 + w[3] * C11;
        acc[0][1] += w[4] * C01 + w[5] * C11;
        acc[0][2] += w[6] * C01 + w[7] * C02 + w[8] * C11 + w[9] * C12;
        acc[1][0] += w[10] * C10 + w[11] * C11;
        acc[1][1] += w[12] * C11;
        acc[1][2] += w[13] * C11 + w[14] * C12;
        acc[2][0] += w[15] * C10 + w[16] * C11 + w[17] * C20 + w[18] * C21;
        acc[2][1] += w[19] * C11 + w[20] * C21;
        acc[2][2] += w[21] * C11 + w[22] * C12 + w[23] * C21 + w[24] * C22;
    }

    const size_t base = ((size_t)(b * 320 + o)) * 4096;
    const int rowmap[4] = {0, 1, 1, 2};
#pragma unroll
    for (int py = 0; py < 4; ++py) {
        const int r = rowmap[py];
        const float4 v = make_float4(acc[r][0], acc[r][1], acc[r][1], acc[r][2]);
        *reinterpret_cast<float4*>(out + base + (cy * 4 + py) * 64 + cx * 4) = v;
    }
}

extern "C" void kernel_launch(void* const* d_in, const int* in_sizes, int n_in,
                              void* d_out, int out_size, void* d_ws, size_t ws_size,
                              hipStream_t stream) {
    const float* x       = (const float*)d_in[0];
    const float* g1      = (const float*)d_in[1];
    const float* b1      = (const float*)d_in[2];
    const float* w_conv1 = (const float*)d_in[3];
    const float* b_conv1 = (const float*)d_in[4];
    const float* ga      = (const float*)d_in[5];
    const float* ba      = (const float*)d_in[6];
    const float* w_qkv   = (const float*)d_in[7];
    const float* b_qkv   = (const float*)d_in[8];
    const float* w_proj  = (const float*)d_in[9];
    const float* b_proj  = (const float*)d_in[10];
    const float* ln_g    = (const float*)d_in[11];
    const float* ln_b    = (const float*)d_in[12];
    const float* w_fc1   = (const float*)d_in[13];
    const float* b_fc1   = (const float*)d_in[14];
    const float* w_fc2   = (const float*)d_in[15];
    const float* b_fc2   = (const float*)d_in[16];
    const float* g2      = (const float*)d_in[17];
    const float* b2      = (const float*)d_in[18];
    const float* w_conv2 = (const float*)d_in[19];
    const float* b_conv2 = (const float*)d_in[20];

    float* z0p  = (float*)d_ws;           //   524,288 (16 b x 16 chunks x 2048)
    float* z0   = z0p + 524288;           //    32,768
    float* a2   = z0 + 32768;             //    32,768
    float* aout = a2 + 32768;             //    32,768
    float* cmb  = aout + 32768;           //    64,000 (320 o x 8 c x 25 combos)
    float* out = (float*)d_out;

    k12_pool_gn_conv<<<266, 256, 0, stream>>>(x, g1, b1, w_conv1, z0p, w_conv2, cmb);
    k3a_attn<<<64, 256, 0, stream>>>(z0p, b_conv1, ga, ba, w_qkv, b_qkv, z0, aout);
    k3c_post<<<16, 256, 0, stream>>>(z0, aout, w_proj, b_proj, ln_g, ln_b,
                                     w_fc1, b_fc1, w_fc2, b_fc2, g2, b2, a2);
    k4_conv2<<<dim3(320, 16), 256, 0, stream>>>(a2, cmb, b_conv2, out);
}